// Round 10
// baseline (238.263 us; speedup 1.0000x reference)
//
#include <hip/hip_runtime.h>

#define L_SEQ 100
#define E_DIM 100
#define G_DIM 192   // 3*H
#define B_TOT 4096
#define L2E   1.4426950408889634f

typedef __attribute__((ext_vector_type(8))) short bf16x8;
typedef __attribute__((ext_vector_type(4))) float f32x4;
typedef __attribute__((ext_vector_type(4))) float float4v;
typedef __attribute__((ext_vector_type(2))) float float2v;
typedef __attribute__((ext_vector_type(4))) unsigned uint4v;
typedef __attribute__((ext_vector_type(2))) unsigned uint2v;

#define MFMA16 __builtin_amdgcn_mfma_f32_16x16x32_bf16

static __device__ __forceinline__ unsigned short f2bf(float f) {
    union { float f; unsigned u; } v; v.f = f;
    unsigned r = v.u + 0x7FFFu + ((v.u >> 16) & 1u);  // RNE
    return (unsigned short)(r >> 16);
}
static __device__ __forceinline__ unsigned cvtpk(float lo, float hi) {
    unsigned r;
    asm("v_cvt_pk_bf16_f32 %0, %1, %2" : "=v"(r) : "v"(lo), "v"(hi));
    return r;
}
static __device__ __forceinline__ bf16x8 as_bf16x8(uint4v u) {
    union { uint4v u; bf16x8 h; } v; v.u = u; return v.h;
}
static __device__ __forceinline__ float rcpf_(float x) { return __builtin_amdgcn_rcpf(x); }

// raw barrier: drains LDS ops only (keeps global prefetch in flight — no vmcnt drain)
#define BAR() do { \
    asm volatile("s_waitcnt lgkmcnt(0)" ::: "memory"); \
    __builtin_amdgcn_s_barrier(); \
    asm volatile("" ::: "memory"); \
} while (0)

struct XBuf { f32x4 v[6]; f32x4 tail; };
struct TiRegs { float4v a0, a1, a2; float rtiF, cF; };   // L2E-scaled ti + precomputed norm coeffs

static __device__ __forceinline__ int tmod(int c) {
    int t = c;
    if (t >= L_SEQ) t -= L_SEQ;
    if (t >= L_SEQ) t -= L_SEQ;
    if (t >= L_SEQ) t -= L_SEQ;
    return t;
}

static __device__ __forceinline__ void x_pf(
    XBuf& b, const float* __restrict__ xlane, const float* __restrict__ xrow, int c, bool g0)
{
    const int t = tmod(c);
    const float* p = xlane + t * E_DIM;
    b.v[0] = *(const f32x4*)(p);
    b.v[1] = *(const f32x4*)(p + 4);
    b.v[2] = *(const f32x4*)(p + 32);
    b.v[3] = *(const f32x4*)(p + 36);
    b.v[4] = *(const f32x4*)(p + 64);
    b.v[5] = *(const f32x4*)(p + 68);
    const f32x4 z = {0.f, 0.f, 0.f, 0.f};
    b.tail = g0 ? *(const f32x4*)(xrow + t * E_DIM + 96) : z;
}

// ti-wave: ti[c] = L2E*(x[c]@Win + bin) -> LDS ring slot c&1 + stat partials
static __device__ __forceinline__ void produce(
    XBuf& xb, const float* __restrict__ xlane, const float* __restrict__ xrow,
    int c, bool g0, float* __restrict__ tird, float* __restrict__ sltiw,
    const bf16x8 (&awin)[3][4], const float (&binq)[12])
{
    bf16x8 bx0 = as_bf16x8((uint4v){cvtpk(xb.v[0][0], xb.v[0][1]), cvtpk(xb.v[0][2], xb.v[0][3]),
                                    cvtpk(xb.v[1][0], xb.v[1][1]), cvtpk(xb.v[1][2], xb.v[1][3])});
    bf16x8 bx1 = as_bf16x8((uint4v){cvtpk(xb.v[2][0], xb.v[2][1]), cvtpk(xb.v[2][2], xb.v[2][3]),
                                    cvtpk(xb.v[3][0], xb.v[3][1]), cvtpk(xb.v[3][2], xb.v[3][3])});
    bf16x8 bx2 = as_bf16x8((uint4v){cvtpk(xb.v[4][0], xb.v[4][1]), cvtpk(xb.v[4][2], xb.v[4][3]),
                                    cvtpk(xb.v[5][0], xb.v[5][1]), cvtpk(xb.v[5][2], xb.v[5][3])});
    bf16x8 bx3 = as_bf16x8((uint4v){cvtpk(xb.tail[0], xb.tail[1]), cvtpk(xb.tail[2], xb.tail[3]),
                                    0u, 0u});
    x_pf(xb, xlane, xrow, c + 2, g0);   // refill this buffer for produce-arg c+2

    const f32x4 zero = {0.f, 0.f, 0.f, 0.f};
    f32x4 t0 = MFMA16(awin[0][0], bx0, zero, 0, 0, 0);
    f32x4 t1 = MFMA16(awin[1][0], bx0, zero, 0, 0, 0);
    f32x4 t2 = MFMA16(awin[2][0], bx0, zero, 0, 0, 0);
    t0 = MFMA16(awin[0][1], bx1, t0, 0, 0, 0);
    t1 = MFMA16(awin[1][1], bx1, t1, 0, 0, 0);
    t2 = MFMA16(awin[2][1], bx1, t2, 0, 0, 0);
    t0 = MFMA16(awin[0][2], bx2, t0, 0, 0, 0);
    t1 = MFMA16(awin[1][2], bx2, t1, 0, 0, 0);
    t2 = MFMA16(awin[2][2], bx2, t2, 0, 0, 0);
    t0 = MFMA16(awin[0][3], bx3, t0, 0, 0, 0);
    t1 = MFMA16(awin[1][3], bx3, t1, 0, 0, 0);
    t2 = MFMA16(awin[2][3], bx3, t2, 0, 0, 0);

    const int par = c & 1;
    float4v A0 = {t0[0] + binq[0], t0[1] + binq[1], t0[2] + binq[2],  t0[3] + binq[3]};
    float4v A1 = {t1[0] + binq[4], t1[1] + binq[5], t1[2] + binq[6],  t1[3] + binq[7]};
    float4v A2 = {t2[0] + binq[8], t2[1] + binq[9], t2[2] + binq[10], t2[3] + binq[11]};
    float* dst = tird + par * 3328;     // parity stride = 4*16*52 floats
    *(float4v*)(dst)     = A0;
    *(float4v*)(dst + 4) = A1;
    *(float4v*)(dst + 8) = A2;

    float s = ((A0[0] + A0[1]) + (A0[2] + A0[3])) + ((A1[0] + A1[1]) + (A1[2] + A1[3]))
            + ((A2[0] + A2[1]) + (A2[2] + A2[3]));
    float ss = 0.f;
    #pragma unroll
    for (int k2 = 0; k2 < 4; ++k2) ss = fmaf(A0[k2], A0[k2], ss);
    #pragma unroll
    for (int k2 = 0; k2 < 4; ++k2) ss = fmaf(A1[k2], A1[k2], ss);
    #pragma unroll
    for (int k2 = 0; k2 < 4; ++k2) ss = fmaf(A2[k2], A2[k2], ss);
    s  += __shfl_xor(s, 16);  s  += __shfl_xor(s, 32);
    ss += __shfl_xor(ss, 16); ss += __shfl_xor(ss, 32);
    if (g0) *(float2v*)(sltiw + par * 192) = (float2v){s, ss};
}

// h-wave late-read: ti regs + precomputed normalization coeffs for the NEXT step (off-chain)
static __device__ __forceinline__ void lr_load(
    TiRegs& R, int slot, const float* __restrict__ tird, const float* __restrict__ sltir)
{
    const float* src = tird + slot * 3328;
    R.a0 = *(const float4v*)(src);
    R.a1 = *(const float4v*)(src + 4);
    R.a2 = *(const float4v*)(src + 8);
    const float* sp = sltir + slot * 192;
    float4v q0 = *(const float4v*)(sp);
    float4v q1 = *(const float4v*)(sp + 4);
    float S  = (q0[0] + q0[2]) + (q1[0] + q1[2]);
    float SS = (q0[1] + q0[3]) + (q1[1] + q1[3]);
    float m  = S * (1.f / G_DIM);
    float var = (SS - (float)G_DIM * m * m) * (1.f / (G_DIM - 1));
    float r = __builtin_amdgcn_rsqf(fmaxf(var, 1e-24f)) * L2E;
    R.rtiF = r;
    R.cF   = m * r;
}

__global__ __launch_bounds__(512, 1) void gru_ws(
    const float* __restrict__ x,
    const float* __restrict__ Win, const float* __restrict__ bin,
    const float* __restrict__ Wh,  const float* __restrict__ bh,
    const float* __restrict__ Wfc, const float* __restrict__ bfc,
    float* __restrict__ out)
{
    __shared__ __align__(16) unsigned short hs[2][16][72];   // h ring [parity][row][hdim]
    __shared__ __align__(16) float tir[2][4][16][52];        // ti ring (L2E-scaled)
    __shared__ __align__(16) float slti[2][16][12];          // ti stat partials {s,ss}/wave
    __shared__ __align__(16) float slth[2][16][12];          // th stat partials

    const int tid = threadIdx.x;
    const int wv  = tid >> 6;
    const int w   = wv & 3;
    const bool tirole = (wv >= 4);
    const int l = tid & 63, c16 = l & 15, g = l >> 4;
    const bool g0 = (g == 0);
    const int row0 = blockIdx.x * 16;

    bf16x8 awin[3][4]; float binq[12];
    bf16x8 awh[3][2];  float bhqL[12];
    const float* xrow = nullptr; const float* xlane = nullptr;

    if (tirole) {
        #pragma unroll
        for (int i = 0; i < 3; ++i)
          #pragma unroll
          for (int kt = 0; kt < 4; ++kt)
            #pragma unroll
            for (int j = 0; j < 8; ++j) {
                int k = 32 * kt + 8 * g + j;
                float v = (k < E_DIM) ? Win[k * G_DIM + 16 * (w + 4 * i) + c16] * L2E : 0.f;
                awin[i][kt][j] = (short)f2bf(v);
            }
        #pragma unroll
        for (int i = 0; i < 3; ++i)
          #pragma unroll
          for (int rr = 0; rr < 4; ++rr)
              binq[4 * i + rr] = bin[16 * (w + 4 * i) + 4 * g + rr] * L2E;
        xrow  = x + (size_t)(row0 + c16) * (L_SEQ * E_DIM);
        xlane = xrow + 8 * g;
    } else {
        #pragma unroll
        for (int i = 0; i < 3; ++i)
          #pragma unroll
          for (int kt = 0; kt < 2; ++kt)
            #pragma unroll
            for (int j = 0; j < 8; ++j)
                awh[i][kt][j] = (short)f2bf(Wh[(32 * kt + 8 * g + j) * G_DIM + 16 * (w + 4 * i) + c16] * L2E);
        #pragma unroll
        for (int i = 0; i < 3; ++i)
          #pragma unroll
          for (int rr = 0; rr < 4; ++rr)
              bhqL[4 * i + rr] = bh[16 * (w + 4 * i) + 4 * g + rr] * L2E;
        bf16x8 z = {0, 0, 0, 0, 0, 0, 0, 0};
        *(bf16x8*)&hs[0][c16][8 * g]      = z;
        *(bf16x8*)&hs[0][c16][32 + 8 * g] = z;
    }

    float* tird        = &tir[0][w][c16][g * 12];
    float* sltiw       = &slti[0][c16][2 * w];
    float* slthw       = &slth[0][c16][2 * w];
    const float* sltir = &slti[0][c16][0];
    const float* slthr = &slth[0][c16][0];

    float hreg[4] = {0.f, 0.f, 0.f, 0.f};

    XBuf xA, xB;
    if (tirole) {
        x_pf(xA, xlane, xrow, 0, g0);
        x_pf(xB, xlane, xrow, 1, g0);
        produce(xA, xlane, xrow, 0, g0, tird, sltiw, awin, binq);   // refills xA for c=2
        produce(xB, xlane, xrow, 1, g0, tird, sltiw, awin, binq);   // refills xB for c=3
    }
    BAR();

    TiRegs RA, RB;
    if (!tirole) {
        lr_load(RA, 0, tird, sltir);          // step 0's ti
        __builtin_amdgcn_s_setprio(1);        // favor recurrent critical path (T5)
    }

    auto HGEMM = [&](int par, float (&b)[12]) {
        bf16x8 h0 = *(const bf16x8*)&hs[par][c16][8 * g];
        bf16x8 h1 = *(const bf16x8*)&hs[par][c16][32 + 8 * g];
        const f32x4 zero = {0.f, 0.f, 0.f, 0.f};
        f32x4 t0 = MFMA16(awh[0][0], h0, zero, 0, 0, 0);
        f32x4 t1 = MFMA16(awh[1][0], h0, zero, 0, 0, 0);
        f32x4 t2 = MFMA16(awh[2][0], h0, zero, 0, 0, 0);
        t0 = MFMA16(awh[0][1], h1, t0, 0, 0, 0);
        t1 = MFMA16(awh[1][1], h1, t1, 0, 0, 0);
        t2 = MFMA16(awh[2][1], h1, t2, 0, 0, 0);
        #pragma unroll
        for (int rr = 0; rr < 4; ++rr) {
            b[rr]     = t0[rr] + bhqL[rr];
            b[4 + rr] = t1[rr] + bhqL[4 + rr];
            b[8 + rr] = t2[rr] + bhqL[8 + rr];
        }
    };
    auto HWRITE = [&](int par, float (&hn)[4]) {
        *(uint2v*)&hs[par ^ 1][c16][16 * w + 4 * g] = (uint2v){cvtpk(hn[0], hn[1]), cvtpk(hn[2], hn[3])};
    };

    // phase-1 h-wave step: gates without norm (all values in L2E domain)
    auto H1 = [&](TiRegs& CUR, TiRegs& NXT, int st) {
        const int par = st & 1;
        float b[12];
        HGEMM(par, b);
        float hn[4];
        #pragma unroll
        for (int rr = 0; rr < 4; ++rr) {
            float er = rcpf_(1.f + __builtin_exp2f(-(CUR.a0[rr] + b[rr])));
            float zt = rcpf_(1.f + __builtin_exp2f(-(CUR.a1[rr] + b[4 + rr])));
            float uL = fmaf(er, b[8 + rr], CUR.a2[rr]);
            float tn = fmaf(2.f, rcpf_(1.f + __builtin_exp2f(-(uL + uL))), -1.f);
            hn[rr] = fmaf(zt, hreg[rr] - tn, tn);
            hreg[rr] = hn[rr];
        }
        HWRITE(par, hn);
        lr_load(NXT, (st + 1) & 1, tird, sltir);   // off-chain: next step's ti + coeffs
    };

    // ---------------- phase 1: 1 barrier/step ----------------
    #pragma unroll 1
    for (int s = 0; s < L_SEQ; s += 2) {
        if (tirole) produce(xA, xlane, xrow, s + 2, g0, tird, sltiw, awin, binq);
        else        H1(RA, RB, s);
        BAR();
        if (tirole) produce(xB, xlane, xrow, s + 3, g0, tird, sltiw, awin, binq);
        else        H1(RB, RA, s + 1);
        BAR();
    }

    // phase-2 h-wave step (CUR has precomputed rtiF/cF)
    auto H2 = [&](TiRegs& CUR, TiRegs& NXT, int st) {
        const int par = st & 1;
        float b[12];
        HGEMM(par, b);
        float sb = 0.f, ssb = 0.f;
        #pragma unroll
        for (int k2 = 0; k2 < 12; ++k2) { sb += b[k2]; ssb = fmaf(b[k2], b[k2], ssb); }
        sb  += __shfl_xor(sb, 16);  sb  += __shfl_xor(sb, 32);
        ssb += __shfl_xor(ssb, 16); ssb += __shfl_xor(ssb, 32);
        if (g0) *(float2v*)(slthw + par * 192) = (float2v){sb, ssb};
        BAR();   // mid: th partials visible
        const float* sp = slthr + par * 192;
        float4v q0 = *(const float4v*)(sp);
        float4v q1 = *(const float4v*)(sp + 4);
        float S  = (q0[0] + q0[2]) + (q1[0] + q1[2]);
        float SS = (q0[1] + q0[3]) + (q1[1] + q1[3]);
        float m  = S * (1.f / G_DIM);
        float var = (SS - (float)G_DIM * m * m) * (1.f / (G_DIM - 1));
        float rthF = __builtin_amdgcn_rsqf(fmaxf(var, 1e-24f)) * L2E;
        float chF  = m * rthF;
        float hn[4];
        #pragma unroll
        for (int rr = 0; rr < 4; ++rr) {
            float ntr = fmaf(CUR.a0[rr], CUR.rtiF, -CUR.cF);
            float ntz = fmaf(CUR.a1[rr], CUR.rtiF, -CUR.cF);
            float ntn = fmaf(CUR.a2[rr], CUR.rtiF, -CUR.cF);
            float nhr = fmaf(b[rr],     rthF, -chF);
            float nhz = fmaf(b[4 + rr], rthF, -chF);
            float nhn = fmaf(b[8 + rr], rthF, -chF);
            float er = rcpf_(1.f + __builtin_exp2f(-(ntr + nhr)));
            float zt = rcpf_(1.f + __builtin_exp2f(-(ntz + nhz)));
            float uL = fmaf(er, nhn, ntn);
            float tn = fmaf(2.f, rcpf_(1.f + __builtin_exp2f(-(uL + uL))), -1.f);
            hn[rr] = fmaf(zt, hreg[rr] - tn, tn);
            hreg[rr] = hn[rr];
        }
        HWRITE(par, hn);
        lr_load(NXT, (st + 1) & 1, tird, sltir);
    };

    // ---------------- phase 2: 2 barriers/step ----------------
    #pragma unroll 1
    for (int s = L_SEQ; s < 2 * L_SEQ; s += 2) {
        if (tirole) { produce(xA, xlane, xrow, s + 2, g0, tird, sltiw, awin, binq); BAR(); }
        else        H2(RA, RB, s);           // contains the mid-BAR
        BAR();
        if (tirole) { produce(xB, xlane, xrow, s + 3, g0, tird, sltiw, awin, binq); BAR(); }
        else        H2(RB, RA, s + 1);
        BAR();
    }

    // ---------------- epilogue: out = h @ W_fc + b_fc ----------------
    if (!tirole) {
        float po0 = 0.f, po1 = 0.f;
        #pragma unroll
        for (int rr = 0; rr < 4; ++rr) {
            int c = 16 * w + 4 * g + rr;
            po0 = fmaf(hreg[rr], Wfc[2 * c],     po0);
            po1 = fmaf(hreg[rr], Wfc[2 * c + 1], po1);
        }
        po0 += __shfl_xor(po0, 16); po0 += __shfl_xor(po0, 32);
        po1 += __shfl_xor(po1, 16); po1 += __shfl_xor(po1, 32);
        if (g0) *(float2v*)(slthw) = (float2v){po0, po1};
    }
    BAR();
    if (tid < 16) {
        const float* sp = &slth[0][tid][0];
        float4v q0 = *(const float4v*)(sp);
        float4v q1 = *(const float4v*)(sp + 4);
        out[(row0 + tid) * 2 + 0] = (q0[0] + q0[2]) + (q1[0] + q1[2]) + bfc[0];
        out[(row0 + tid) * 2 + 1] = (q0[1] + q0[3]) + (q1[1] + q1[3]) + bfc[1];
    }
}

extern "C" void kernel_launch(void* const* d_in, const int* in_sizes, int n_in,
                              void* d_out, int out_size, void* d_ws, size_t ws_size,
                              hipStream_t stream) {
    const float* x   = (const float*)d_in[0];
    const float* Win = (const float*)d_in[1];
    const float* bin = (const float*)d_in[2];
    const float* Wh  = (const float*)d_in[3];
    const float* bh  = (const float*)d_in[4];
    const float* Wfc = (const float*)d_in[5];
    const float* bfc = (const float*)d_in[6];
    float* out = (float*)d_out;
    gru_ws<<<dim3(B_TOT / 16), dim3(512), 0, stream>>>(
        x, Win, bin, Wh, bh, Wfc, bfc, out);
}